// Round 1
// baseline (39467.697 us; speedup 1.0000x reference)
//
#include <hip/hip_runtime.h>
#include <math.h>

#define BB 256
#define NN 184
#define HH 128
#define FF 8
#define TH 24
#define TF 24
#define BN (BB*NN)   // 47104

__device__ __forceinline__ float sigmoidf_(float x) {
    return 1.0f / (1.0f + __expf(-x));
}
__device__ __forceinline__ float tanhf_(float x) {
    float s = (x >= 0.f) ? 1.f : -1.f;
    float e = __expf(-2.0f * fabsf(x));
    return s * (1.0f - e) / (1.0f + e);
}

// ---------------------------------------------------------------------------
// precompute comp1 = cos(angles), comp2 = cos(angles - pi/2)
// ---------------------------------------------------------------------------
__global__ void precomp_kernel(const float* __restrict__ angles,
                               float* __restrict__ c1, float* __restrict__ c2) {
    int i = blockIdx.x * 256 + threadIdx.x;
    if (i < NN * NN) {
        float a = angles[i];
        c1[i] = cosf(a);
        c2[i] = cosf(a - 1.57079632679489662f);
    }
}

// ---------------------------------------------------------------------------
// Fused GRU step. 64 rows/block, 256 threads. thread j = tid&127 owns hidden
// column j (gate rows j, 128+j, 256+j); halves (tid>>7) split 64 rows into 32.
// HIST mode: input x = [xn, p] with xn = fc_hist(h_prev) computed in-kernel.
// FORE mode: input x2[BN,10] read from global (written by graph kernel).
// ---------------------------------------------------------------------------
template<int IND, bool HIST>
__global__ __launch_bounds__(256, 2) void gru_step(
    float* __restrict__ h,             // [BN, 128], updated in place
    const float* __restrict__ xin,     // HIST: pm25 + t*NN ; FORE: x2 [BN,10]
    const float* __restrict__ Wih,     // [384, IND]
    const float* __restrict__ Whh,     // [384, 128]
    const float* __restrict__ bih,
    const float* __restrict__ bhh,
    const float* __restrict__ fcw,     // HIST only: [128]
    const float* __restrict__ fcb,     // HIST only: [1]
    int first)
{
    __shared__ float h_s[64 * 132];        // padded row stride 132
    __shared__ float x_s[64 * IND];
    __shared__ float part[4][64];

    const int tid = threadIdx.x;
    const long rowbase = (long)blockIdx.x * 64;

    // stage h tile (64x128 floats, float4-vectorized, coalesced)
    const float4* hg = reinterpret_cast<const float4*>(h + rowbase * HH);
    #pragma unroll
    for (int it = 0; it < 8; ++it) {
        int f4 = tid + it * 256;           // 0..2047
        int row = f4 >> 5;                 // 32 float4 per row
        int k4 = f4 & 31;
        float4 v = hg[f4];
        *reinterpret_cast<float4*>(&h_s[row * 132 + k4 * 4]) = v;
    }
    __syncthreads();

    if (HIST) {
        // xn = fc_hist(h_prev) per row (4 threads/row partials)
        int row = tid & 63, q = tid >> 6;
        float s = 0.f;
        if (!first) {
            #pragma unroll 8
            for (int k = q * 32; k < q * 32 + 32; ++k)
                s += fcw[k] * h_s[row * 132 + k];
        }
        part[q][row] = s;
        __syncthreads();
        if (tid < 64) {
            long rg = rowbase + tid;
            int b = (int)(rg / NN), n = (int)(rg - (long)b * NN);
            float xn = first ? 0.f
                             : (part[0][tid] + part[1][tid] + part[2][tid] + part[3][tid] + fcb[0]);
            x_s[tid * 2 + 0] = xn;
            x_s[tid * 2 + 1] = xin[(long)b * (TH * NN) + n];   // pm25[b, t, n]
        }
        __syncthreads();
    } else {
        for (int i = tid; i < 64 * IND; i += 256)
            x_s[i] = xin[rowbase * IND + i];
        __syncthreads();
    }

    const int j = tid & 127;
    const int rb = (tid >> 7) * 32;

    float accR[32], accZ[32], accN[32];
    #pragma unroll
    for (int r = 0; r < 32; ++r) { accR[r] = 0.f; accZ[r] = 0.f; accN[r] = 0.f; }

    const float4* WR = reinterpret_cast<const float4*>(Whh + (long)j * HH);
    const float4* WZ = reinterpret_cast<const float4*>(Whh + (long)(HH + j) * HH);
    const float4* WN = reinterpret_cast<const float4*>(Whh + (long)(2 * HH + j) * HH);

    for (int kc = 0; kc < 16; ++kc) {
        float4 wr0 = WR[kc * 2], wr1 = WR[kc * 2 + 1];
        float4 wz0 = WZ[kc * 2], wz1 = WZ[kc * 2 + 1];
        float4 wn0 = WN[kc * 2], wn1 = WN[kc * 2 + 1];
        #pragma unroll
        for (int r = 0; r < 32; ++r) {
            const float* hp = &h_s[(rb + r) * 132 + kc * 8];
            float4 h0 = *reinterpret_cast<const float4*>(hp);
            float4 h1 = *reinterpret_cast<const float4*>(hp + 4);
            accR[r] += wr0.x * h0.x + wr0.y * h0.y + wr0.z * h0.z + wr0.w * h0.w
                     + wr1.x * h1.x + wr1.y * h1.y + wr1.z * h1.z + wr1.w * h1.w;
            accZ[r] += wz0.x * h0.x + wz0.y * h0.y + wz0.z * h0.z + wz0.w * h0.w
                     + wz1.x * h1.x + wz1.y * h1.y + wz1.z * h1.z + wz1.w * h1.w;
            accN[r] += wn0.x * h0.x + wn0.y * h0.y + wn0.z * h0.z + wn0.w * h0.w
                     + wn1.x * h1.x + wn1.y * h1.y + wn1.z * h1.z + wn1.w * h1.w;
        }
    }

    // epilogue: gates + state update
    const float bihR = bih[j], bihZ = bih[HH + j], bihN = bih[2 * HH + j];
    const float bhhR = bhh[j], bhhZ = bhh[HH + j], bhhN = bhh[2 * HH + j];
    float wiR[IND], wiZ[IND], wiN[IND];
    #pragma unroll
    for (int d = 0; d < IND; ++d) {
        wiR[d] = Wih[(long)j * IND + d];
        wiZ[d] = Wih[(long)(HH + j) * IND + d];
        wiN[d] = Wih[(long)(2 * HH + j) * IND + d];
    }

    #pragma unroll
    for (int r = 0; r < 32; ++r) {
        int row = rb + r;
        float giR = bihR, giZ = bihZ, giN = bihN;
        #pragma unroll
        for (int d = 0; d < IND; ++d) {
            float xv = x_s[row * IND + d];
            giR += wiR[d] * xv; giZ += wiZ[d] * xv; giN += wiN[d] * xv;
        }
        float rg = sigmoidf_(giR + accR[r] + bhhR);
        float zg = sigmoidf_(giZ + accZ[r] + bhhZ);
        float ng = tanhf_(giN + rg * (accN[r] + bhhN));
        float hp = h_s[row * 132 + j];
        float hn = (1.f - zg) * ng + zg * hp;
        h[(rowbase + row) * HH + j] = hn;
    }
}

// ---------------------------------------------------------------------------
// Graph step: one block per batch b. Computes xn = fc(h) (writes preds[t-1]
// for t>0), wind-gated adjacency bitmask, ChebConv y, gate g, and x2 [BN,10].
// ---------------------------------------------------------------------------
__global__ __launch_bounds__(256) void graph_step(
    const float* __restrict__ h,          // [BN,128]
    const float* __restrict__ feature_t,  // feature + (TH+t)*NN*FF
    const float* __restrict__ comp1,
    const float* __restrict__ comp2,
    const float* __restrict__ adj,
    const float* __restrict__ fcw,        // t==0: fc_hist, else fc_out
    const float* __restrict__ fcb,
    const float* __restrict__ w0,         // cheb_w0 [9]
    const float* __restrict__ w1,         // cheb_w1 [9]
    const float* __restrict__ cb,         // cheb_b [1]
    float* __restrict__ x2,               // [BN,10]
    float* __restrict__ pred,             // [B,TF,NN]
    int t)
{
    const int b = blockIdx.x;
    const int tid = threadIdx.x;

    __shared__ float fs[NN * FF];
    __shared__ float xs[NN * 9];
    __shared__ float dinv_s[NN];
    __shared__ float hz_s[NN];
    __shared__ unsigned long long mask_s[NN][3];

    const float* fbase = feature_t + (long)b * (48 * NN * FF);
    for (int i = tid; i < NN * FF; i += 256) fs[i] = fbase[i];

    // xn = fc(h[b,n,:]) + fcb
    float xnv = 0.f;
    if (tid < NN) {
        const float* hr = h + ((long)b * NN + tid) * HH;
        float s = 0.f;
        #pragma unroll 8
        for (int k = 0; k < HH; ++k) s += fcw[k] * hr[k];
        xnv = s + fcb[0];
    }
    __syncthreads();   // fs ready

    if (tid < NN) {
        if (t > 0) pred[((long)b * TF + (t - 1)) * NN + tid] = xnv;
        xs[tid * 9 + 0] = xnv;
        #pragma unroll
        for (int c = 0; c < FF; ++c) xs[tid * 9 + 1 + c] = fs[tid * FF + c];

        // phase A: wind-gated edge mask + source degree (row i)
        int i = tid;
        float u = fs[i * FF + 0], v = fs[i * FF + 1];
        const float* c1 = comp1 + (long)i * NN;
        const float* c2 = comp2 + (long)i * NN;
        const float* ad = adj + (long)i * NN;
        unsigned long long m0 = 0ull, m1 = 0ull, m2 = 0ull;
        int deg = 0;
        for (int jj = 0; jj < NN; ++jj) {
            float wind = u * c1[jj] + v * c2[jj];
            bool e = (wind >= 0.5f) && (ad[jj] > 0.f);
            if (e) {
                deg++;
                if (jj < 64)       m0 |= 1ull << jj;
                else if (jj < 128) m1 |= 1ull << (jj - 64);
                else               m2 |= 1ull << (jj - 128);
            }
        }
        mask_s[i][0] = m0; mask_s[i][1] = m1; mask_s[i][2] = m2;
        dinv_s[i] = (deg > 0) ? rsqrtf((float)deg) : 0.f;
        hz_s[i] = (deg > 0) ? 0.f : -1.f;
    }
    __syncthreads();   // xs, mask, dinv ready

    // phase B: y[j,c] = sum_i M[i,j]*dinv[i]*x[i,c] ; then g, x2
    if (tid < NN) {
        int jj = tid;
        int w = jj >> 6, bit = jj & 63;
        float acc[9];
        #pragma unroll
        for (int c = 0; c < 9; ++c) acc[c] = 0.f;
        for (int i = 0; i < NN; ++i) {
            if ((mask_s[i][w] >> bit) & 1ull) {
                float d = dinv_s[i];
                #pragma unroll
                for (int c = 0; c < 9; ++c) acc[c] += d * xs[i * 9 + c];
            }
        }
        float dj = dinv_s[jj], hzj = hz_s[jj];
        float gsum = cb[0];
        float* out = x2 + ((long)b * NN + jj) * 10;
        #pragma unroll
        for (int c = 0; c < 9; ++c) {
            float xv = xs[jj * 9 + c];
            float y = -dj * acc[c] + hzj * xv;
            gsum += xv * w0[c] + y * w1[c];
            out[c] = xv;
        }
        out[9] = sigmoidf_(gsum);
    }
}

// ---------------------------------------------------------------------------
// final prediction slot t=TF-1: pred[:,23,:] = fc_out(h)
// ---------------------------------------------------------------------------
__global__ void final_pred(const float* __restrict__ h,
                           const float* __restrict__ fcw,
                           const float* __restrict__ fcb,
                           float* __restrict__ pred) {
    long r = (long)blockIdx.x * 256 + threadIdx.x;
    if (r < BN) {
        int b = (int)(r / NN), n = (int)(r - (long)b * NN);
        const float* hr = h + r * HH;
        float s = 0.f;
        #pragma unroll 8
        for (int k = 0; k < HH; ++k) s += fcw[k] * hr[k];
        pred[((long)b * TF + (TF - 1)) * NN + n] = s + fcb[0];
    }
}

extern "C" void kernel_launch(void* const* d_in, const int* in_sizes, int n_in,
                              void* d_out, int out_size, void* d_ws, size_t ws_size,
                              hipStream_t stream) {
    const float* feature = (const float*)d_in[0];
    const float* pm25    = (const float*)d_in[1];
    const float* adj     = (const float*)d_in[2];
    const float* angles  = (const float*)d_in[3];
    const float* W_ih_h  = (const float*)d_in[4];
    const float* W_hh_h  = (const float*)d_in[5];
    const float* b_ih_h  = (const float*)d_in[6];
    const float* b_hh_h  = (const float*)d_in[7];
    const float* fch_w   = (const float*)d_in[8];
    const float* fch_b   = (const float*)d_in[9];
    const float* cw0     = (const float*)d_in[10];
    const float* cw1     = (const float*)d_in[11];
    const float* cbb     = (const float*)d_in[12];
    const float* W_ih    = (const float*)d_in[13];
    const float* W_hh    = (const float*)d_in[14];
    const float* b_ih    = (const float*)d_in[15];
    const float* b_hh    = (const float*)d_in[16];
    const float* fco_w   = (const float*)d_in[17];
    const float* fco_b   = (const float*)d_in[18];
    float* pred = (float*)d_out;

    char* ws = (char*)d_ws;
    float* h  = (float*)(ws);                                  // 24,117,248 B
    float* x2 = (float*)(ws + 24117248);                       //  1,884,160 B
    float* c1 = (float*)(ws + 24117248 + 1884160);             //    135,424 B
    float* c2 = c1 + NN * NN;                                  //    135,424 B

    hipMemsetAsync(h, 0, (size_t)BN * HH * sizeof(float), stream);
    precomp_kernel<<<(NN * NN + 255) / 256, 256, 0, stream>>>(angles, c1, c2);

    for (int t = 0; t < TH; ++t) {
        gru_step<2, true><<<BN / 64, 256, 0, stream>>>(
            h, pm25 + (long)t * NN, W_ih_h, W_hh_h, b_ih_h, b_hh_h,
            fch_w, fch_b, (t == 0) ? 1 : 0);
    }

    for (int t = 0; t < TF; ++t) {
        graph_step<<<BB, 256, 0, stream>>>(
            h, feature + (long)(TH + t) * NN * FF, c1, c2, adj,
            (t == 0) ? fch_w : fco_w, (t == 0) ? fch_b : fco_b,
            cw0, cw1, cbb, x2, pred, t);
        gru_step<10, false><<<BN / 64, 256, 0, stream>>>(
            h, x2, W_ih, W_hh, b_ih, b_hh, nullptr, nullptr, 0);
    }

    final_pred<<<NN, 256, 0, stream>>>(h, fco_w, fco_b, pred);
}

// Round 2
// 8823.753 us; speedup vs baseline: 4.4729x; 4.4729x over previous
//
#include <hip/hip_runtime.h>
#include <math.h>

#define BB 256
#define NN 184
#define HH 128
#define FF 8
#define TH 24
#define TF 24
#define BN (BB*NN)   // 47104
#define RT 32        // rows per block tile
#define RG 16        // rows per thread group (2 groups)

__device__ __forceinline__ float sigmoidf_(float x) {
    return 1.0f / (1.0f + __expf(-x));
}
__device__ __forceinline__ float tanhf_(float x) {
    float s = (x >= 0.f) ? 1.f : -1.f;
    float e = __expf(-2.0f * fabsf(x));
    return s * (1.0f - e) / (1.0f + e);
}

// ---------------------------------------------------------------------------
// precompute comp1 = cos(angles), comp2 = cos(angles - pi/2)
// ---------------------------------------------------------------------------
__global__ void precomp_kernel(const float* __restrict__ angles,
                               float* __restrict__ c1, float* __restrict__ c2) {
    int i = blockIdx.x * 256 + threadIdx.x;
    if (i < NN * NN) {
        float a = angles[i];
        c1[i] = cosf(a);
        c2[i] = cosf(a - 1.57079632679489662f);
    }
}

// ---------------------------------------------------------------------------
// Fused GRU step. 32 rows/block, 256 threads. thread j = tid&127 owns hidden
// column j (gate rows j, 128+j, 256+j); group (tid>>7) covers 16 rows.
// 48 accumulators/thread -> no VGPR spill under the 128-reg cap.
// HIST mode: input x = [xn, p] with xn = fc_hist(h_prev) computed in-kernel.
// FORE mode: input x2[BN,10] read from global (written by graph kernel).
// ---------------------------------------------------------------------------
template<int IND, bool HIST>
__global__ __launch_bounds__(256, 2) void gru_step(
    float* __restrict__ h,             // [BN, 128], updated in place
    const float* __restrict__ xin,     // HIST: pm25 + t*NN ; FORE: x2 [BN,10]
    const float* __restrict__ Wih,     // [384, IND]
    const float* __restrict__ Whh,     // [384, 128]
    const float* __restrict__ bih,
    const float* __restrict__ bhh,
    const float* __restrict__ fcw,     // HIST only: [128]
    const float* __restrict__ fcb,     // HIST only: [1]
    int first)
{
    __shared__ float h_s[RT * 132];        // padded row stride 132
    __shared__ float x_s[RT * IND];
    __shared__ float part[8][RT];

    const int tid = threadIdx.x;
    const long rowbase = (long)blockIdx.x * RT;

    // stage h tile (32x128 floats = 1024 float4, coalesced)
    const float4* hg = reinterpret_cast<const float4*>(h + rowbase * HH);
    #pragma unroll
    for (int it = 0; it < 4; ++it) {
        int f4 = tid + it * 256;           // 0..1023
        int row = f4 >> 5;                 // 32 float4 per row
        int k4 = f4 & 31;
        float4 v = hg[f4];
        *reinterpret_cast<float4*>(&h_s[row * 132 + k4 * 4]) = v;
    }
    __syncthreads();

    if (HIST) {
        // xn = fc_hist(h_prev) per row (8 threads/row partials of 16)
        int row = tid & (RT - 1), q = tid >> 5;
        float s = 0.f;
        if (!first) {
            #pragma unroll
            for (int k = q * 16; k < q * 16 + 16; ++k)
                s += fcw[k] * h_s[row * 132 + k];
        }
        part[q][row] = s;
        __syncthreads();
        if (tid < RT) {
            long rg = rowbase + tid;
            int b = (int)(rg / NN), n = (int)(rg - (long)b * NN);
            float xn = 0.f;
            if (!first) {
                xn = fcb[0];
                #pragma unroll
                for (int q2 = 0; q2 < 8; ++q2) xn += part[q2][tid];
            }
            x_s[tid * 2 + 0] = xn;
            x_s[tid * 2 + 1] = xin[(long)b * (TH * NN) + n];   // pm25[b, t, n]
        }
        __syncthreads();
    } else {
        for (int i = tid; i < RT * IND; i += 256)
            x_s[i] = xin[rowbase * IND + i];
        __syncthreads();
    }

    const int j = tid & 127;
    const int rb = (tid >> 7) * RG;

    float accR[RG], accZ[RG], accN[RG];
    #pragma unroll
    for (int r = 0; r < RG; ++r) { accR[r] = 0.f; accZ[r] = 0.f; accN[r] = 0.f; }

    const float4* WR = reinterpret_cast<const float4*>(Whh + (long)j * HH);
    const float4* WZ = reinterpret_cast<const float4*>(Whh + (long)(HH + j) * HH);
    const float4* WN = reinterpret_cast<const float4*>(Whh + (long)(2 * HH + j) * HH);

    for (int kc = 0; kc < 16; ++kc) {
        float4 wr0 = WR[kc * 2], wr1 = WR[kc * 2 + 1];
        float4 wz0 = WZ[kc * 2], wz1 = WZ[kc * 2 + 1];
        float4 wn0 = WN[kc * 2], wn1 = WN[kc * 2 + 1];
        #pragma unroll
        for (int r = 0; r < RG; ++r) {
            const float* hp = &h_s[(rb + r) * 132 + kc * 8];
            float4 h0 = *reinterpret_cast<const float4*>(hp);
            float4 h1 = *reinterpret_cast<const float4*>(hp + 4);
            accR[r] += wr0.x * h0.x + wr0.y * h0.y + wr0.z * h0.z + wr0.w * h0.w
                     + wr1.x * h1.x + wr1.y * h1.y + wr1.z * h1.z + wr1.w * h1.w;
            accZ[r] += wz0.x * h0.x + wz0.y * h0.y + wz0.z * h0.z + wz0.w * h0.w
                     + wz1.x * h1.x + wz1.y * h1.y + wz1.z * h1.z + wz1.w * h1.w;
            accN[r] += wn0.x * h0.x + wn0.y * h0.y + wn0.z * h0.z + wn0.w * h0.w
                     + wn1.x * h1.x + wn1.y * h1.y + wn1.z * h1.z + wn1.w * h1.w;
        }
    }

    // epilogue: gates + state update
    const float bihR = bih[j], bihZ = bih[HH + j], bihN = bih[2 * HH + j];
    const float bhhR = bhh[j], bhhZ = bhh[HH + j], bhhN = bhh[2 * HH + j];
    float wiR[IND], wiZ[IND], wiN[IND];
    #pragma unroll
    for (int d = 0; d < IND; ++d) {
        wiR[d] = Wih[(long)j * IND + d];
        wiZ[d] = Wih[(long)(HH + j) * IND + d];
        wiN[d] = Wih[(long)(2 * HH + j) * IND + d];
    }

    #pragma unroll
    for (int r = 0; r < RG; ++r) {
        int row = rb + r;
        float giR = bihR, giZ = bihZ, giN = bihN;
        #pragma unroll
        for (int d = 0; d < IND; ++d) {
            float xv = x_s[row * IND + d];
            giR += wiR[d] * xv; giZ += wiZ[d] * xv; giN += wiN[d] * xv;
        }
        float rg = sigmoidf_(giR + accR[r] + bhhR);
        float zg = sigmoidf_(giZ + accZ[r] + bhhZ);
        float ng = tanhf_(giN + rg * (accN[r] + bhhN));
        float hp = h_s[row * 132 + j];
        float hn = (1.f - zg) * ng + zg * hp;
        h[(rowbase + row) * HH + j] = hn;
    }
}

// ---------------------------------------------------------------------------
// Graph step: one block per batch b. Computes xn = fc(h) (writes preds[t-1]
// for t>0), wind-gated adjacency bitmask, ChebConv y, gate g, and x2 [BN,10].
// ---------------------------------------------------------------------------
__global__ __launch_bounds__(256) void graph_step(
    const float* __restrict__ h,          // [BN,128]
    const float* __restrict__ feature_t,  // feature + (TH+t)*NN*FF
    const float* __restrict__ comp1,
    const float* __restrict__ comp2,
    const float* __restrict__ adj,
    const float* __restrict__ fcw,        // t==0: fc_hist, else fc_out
    const float* __restrict__ fcb,
    const float* __restrict__ w0,         // cheb_w0 [9]
    const float* __restrict__ w1,         // cheb_w1 [9]
    const float* __restrict__ cb,         // cheb_b [1]
    float* __restrict__ x2,               // [BN,10]
    float* __restrict__ pred,             // [B,TF,NN]
    int t)
{
    const int b = blockIdx.x;
    const int tid = threadIdx.x;

    __shared__ float fs[NN * FF];
    __shared__ float xs[NN * 9];
    __shared__ float dinv_s[NN];
    __shared__ float hz_s[NN];
    __shared__ unsigned long long mask_s[NN][3];

    const float* fbase = feature_t + (long)b * (48 * NN * FF);
    for (int i = tid; i < NN * FF; i += 256) fs[i] = fbase[i];

    // xn = fc(h[b,n,:]) + fcb
    float xnv = 0.f;
    if (tid < NN) {
        const float* hr = h + ((long)b * NN + tid) * HH;
        float s = 0.f;
        #pragma unroll 8
        for (int k = 0; k < HH; ++k) s += fcw[k] * hr[k];
        xnv = s + fcb[0];
    }
    __syncthreads();   // fs ready

    if (tid < NN) {
        if (t > 0) pred[((long)b * TF + (t - 1)) * NN + tid] = xnv;
        xs[tid * 9 + 0] = xnv;
        #pragma unroll
        for (int c = 0; c < FF; ++c) xs[tid * 9 + 1 + c] = fs[tid * FF + c];

        // phase A: wind-gated edge mask + source degree (row i)
        int i = tid;
        float u = fs[i * FF + 0], v = fs[i * FF + 1];
        const float* c1 = comp1 + (long)i * NN;
        const float* c2 = comp2 + (long)i * NN;
        const float* ad = adj + (long)i * NN;
        unsigned long long m0 = 0ull, m1 = 0ull, m2 = 0ull;
        int deg = 0;
        for (int jj = 0; jj < NN; ++jj) {
            float wind = u * c1[jj] + v * c2[jj];
            bool e = (wind >= 0.5f) && (ad[jj] > 0.f);
            if (e) {
                deg++;
                if (jj < 64)       m0 |= 1ull << jj;
                else if (jj < 128) m1 |= 1ull << (jj - 64);
                else               m2 |= 1ull << (jj - 128);
            }
        }
        mask_s[i][0] = m0; mask_s[i][1] = m1; mask_s[i][2] = m2;
        dinv_s[i] = (deg > 0) ? rsqrtf((float)deg) : 0.f;
        hz_s[i] = (deg > 0) ? 0.f : -1.f;
    }
    __syncthreads();   // xs, mask, dinv ready

    // phase B: y[j,c] = sum_i M[i,j]*dinv[i]*x[i,c] ; then g, x2
    if (tid < NN) {
        int jj = tid;
        int w = jj >> 6, bit = jj & 63;
        float acc[9];
        #pragma unroll
        for (int c = 0; c < 9; ++c) acc[c] = 0.f;
        for (int i = 0; i < NN; ++i) {
            if ((mask_s[i][w] >> bit) & 1ull) {
                float d = dinv_s[i];
                #pragma unroll
                for (int c = 0; c < 9; ++c) acc[c] += d * xs[i * 9 + c];
            }
        }
        float dj = dinv_s[jj], hzj = hz_s[jj];
        float gsum = cb[0];
        float* out = x2 + ((long)b * NN + jj) * 10;
        #pragma unroll
        for (int c = 0; c < 9; ++c) {
            float xv = xs[jj * 9 + c];
            float y = -dj * acc[c] + hzj * xv;
            gsum += xv * w0[c] + y * w1[c];
            out[c] = xv;
        }
        out[9] = sigmoidf_(gsum);
    }
}

// ---------------------------------------------------------------------------
// final prediction slot t=TF-1: pred[:,23,:] = fc_out(h)
// ---------------------------------------------------------------------------
__global__ void final_pred(const float* __restrict__ h,
                           const float* __restrict__ fcw,
                           const float* __restrict__ fcb,
                           float* __restrict__ pred) {
    long r = (long)blockIdx.x * 256 + threadIdx.x;
    if (r < BN) {
        int b = (int)(r / NN), n = (int)(r - (long)b * NN);
        const float* hr = h + r * HH;
        float s = 0.f;
        #pragma unroll 8
        for (int k = 0; k < HH; ++k) s += fcw[k] * hr[k];
        pred[((long)b * TF + (TF - 1)) * NN + n] = s + fcb[0];
    }
}

extern "C" void kernel_launch(void* const* d_in, const int* in_sizes, int n_in,
                              void* d_out, int out_size, void* d_ws, size_t ws_size,
                              hipStream_t stream) {
    const float* feature = (const float*)d_in[0];
    const float* pm25    = (const float*)d_in[1];
    const float* adj     = (const float*)d_in[2];
    const float* angles  = (const float*)d_in[3];
    const float* W_ih_h  = (const float*)d_in[4];
    const float* W_hh_h  = (const float*)d_in[5];
    const float* b_ih_h  = (const float*)d_in[6];
    const float* b_hh_h  = (const float*)d_in[7];
    const float* fch_w   = (const float*)d_in[8];
    const float* fch_b   = (const float*)d_in[9];
    const float* cw0     = (const float*)d_in[10];
    const float* cw1     = (const float*)d_in[11];
    const float* cbb     = (const float*)d_in[12];
    const float* W_ih    = (const float*)d_in[13];
    const float* W_hh    = (const float*)d_in[14];
    const float* b_ih    = (const float*)d_in[15];
    const float* b_hh    = (const float*)d_in[16];
    const float* fco_w   = (const float*)d_in[17];
    const float* fco_b   = (const float*)d_in[18];
    float* pred = (float*)d_out;

    char* ws = (char*)d_ws;
    float* h  = (float*)(ws);                                  // 24,117,248 B
    float* x2 = (float*)(ws + 24117248);                       //  1,884,160 B
    float* c1 = (float*)(ws + 24117248 + 1884160);             //    135,424 B
    float* c2 = c1 + NN * NN;                                  //    135,424 B

    hipMemsetAsync(h, 0, (size_t)BN * HH * sizeof(float), stream);
    precomp_kernel<<<(NN * NN + 255) / 256, 256, 0, stream>>>(angles, c1, c2);

    for (int t = 0; t < TH; ++t) {
        gru_step<2, true><<<BN / RT, 256, 0, stream>>>(
            h, pm25 + (long)t * NN, W_ih_h, W_hh_h, b_ih_h, b_hh_h,
            fch_w, fch_b, (t == 0) ? 1 : 0);
    }

    for (int t = 0; t < TF; ++t) {
        graph_step<<<BB, 256, 0, stream>>>(
            h, feature + (long)(TH + t) * NN * FF, c1, c2, adj,
            (t == 0) ? fch_w : fco_w, (t == 0) ? fch_b : fco_b,
            cw0, cw1, cbb, x2, pred, t);
        gru_step<10, false><<<BN / RT, 256, 0, stream>>>(
            h, x2, W_ih, W_hh, b_ih, b_hh, nullptr, nullptr, 0);
    }

    final_pred<<<NN, 256, 0, stream>>>(h, fco_w, fco_b, pred);
}

// Round 3
// 2710.259 us; speedup vs baseline: 14.5623x; 3.2557x over previous
//
#include <hip/hip_runtime.h>
#include <math.h>

#define BB 256
#define NN 184
#define HH 128
#define FF 8
#define TH 24
#define TF 24
#define BN (BB*NN)   // 47104
#define KA 160       // augmented K (128 h + up to 10 x + pad)
#define NG 512       // 4 gate-parts x 128

typedef __attribute__((ext_vector_type(8))) short bf16x8;
typedef __attribute__((ext_vector_type(4))) float f32x4;

__device__ __forceinline__ float sigmoidf_(float x) {
    return 1.0f / (1.0f + __expf(-x));
}
__device__ __forceinline__ float tanhf_(float x) {
    float s = (x >= 0.f) ? 1.f : -1.f;
    float e = __expf(-2.0f * fabsf(x));
    return s * (1.0f - e) / (1.0f + e);
}
__device__ __forceinline__ unsigned short f2bf(float f) {
    unsigned u = __float_as_uint(f);
    u += 0x7fffu + ((u >> 16) & 1u);
    return (unsigned short)(u >> 16);
}

// ---------------------------------------------------------------------------
// Build augmented bf16 weights Wa[512][160] for hist & fore, and bias arrays
// barr[4][128]: R:bih+bhh, Z:bih+bhh, NH:bhh, NX:bih.
// ---------------------------------------------------------------------------
__global__ void prep_weights(const float* __restrict__ WhhH, const float* __restrict__ WihH,
                             const float* __restrict__ WhhF, const float* __restrict__ WihF,
                             const float* __restrict__ bihH, const float* __restrict__ bhhH,
                             const float* __restrict__ bihF, const float* __restrict__ bhhF,
                             unsigned short* __restrict__ WaH, unsigned short* __restrict__ WaF,
                             float* __restrict__ barrH, float* __restrict__ barrF) {
    int idx = blockIdx.x * 256 + threadIdx.x;
    if (idx < NG * KA) {
        int jp = idx / KA, k = idx % KA;
        int j = jp & 127, part = jp >> 7;
        float vh = 0.f, vf = 0.f;
        if (part <= 1) {              // R, Z: combined Whh | Wih
            int row = part * 128 + j;
            if (k < 128) { vh = WhhH[row * 128 + k]; vf = WhhF[row * 128 + k]; }
            else {
                if (k < 130) vh = WihH[row * 2 + (k - 128)];
                if (k < 138) vf = WihF[row * 10 + (k - 128)];
            }
        } else if (part == 2) {       // NH: h part of n-gate
            if (k < 128) { vh = WhhH[(256 + j) * 128 + k]; vf = WhhF[(256 + j) * 128 + k]; }
        } else {                      // NX: x part of n-gate
            if (k >= 128) {
                if (k < 130) vh = WihH[(256 + j) * 2 + (k - 128)];
                if (k < 138) vf = WihF[(256 + j) * 10 + (k - 128)];
            }
        }
        WaH[idx] = f2bf(vh); WaF[idx] = f2bf(vf);
    }
    if (idx < NG) {
        int j = idx & 127, part = idx >> 7;
        float bh, bf2;
        if (part == 0)      { bh = bihH[j] + bhhH[j];             bf2 = bihF[j] + bhhF[j]; }
        else if (part == 1) { bh = bihH[128 + j] + bhhH[128 + j]; bf2 = bihF[128 + j] + bhhF[128 + j]; }
        else if (part == 2) { bh = bhhH[256 + j];                 bf2 = bhhF[256 + j]; }
        else                { bh = bihH[256 + j];                 bf2 = bihF[256 + j]; }
        barrH[idx] = bh; barrF[idx] = bf2;
    }
}

// packed wind table: P[i][j] = adj ? (cos(a), cos(a-pi/2)) : (0,0)
__global__ void prep_P(const float* __restrict__ angles, const float* __restrict__ adj,
                       float2* __restrict__ P) {
    int i = blockIdx.x * 256 + threadIdx.x;
    if (i < NN * NN) {
        float a = angles[i];
        bool e = adj[i] > 0.f;
        float2 p; p.x = e ? cosf(a) : 0.f; p.y = e ? cosf(a - 1.57079632679489662f) : 0.f;
        P[i] = p;
    }
}

// A col 129 = pm25[b,0,n] for hist step 0 (rest of A already memset 0)
__global__ void init_hist_x(const float* __restrict__ pm25, unsigned short* __restrict__ A) {
    long r = (long)blockIdx.x * 256 + threadIdx.x;
    if (r < BN) {
        int b = (int)(r / NN), n = (int)(r - (long)b * NN);
        A[r * KA + 129] = f2bf(pm25[(long)b * (TH * NN) + n]);
    }
}

// ---------------------------------------------------------------------------
// MFMA GRU step. 64 rows/block, 4 waves. Wave w owns output cols [32w,32w+32)
// for all 4 gate-parts (R,Z,NH,NX). A[BN][160] bf16 = [h | x | pad].
// Epilogue: gates + h update (fp32 + bf16 copies); hist_next: xn=fc(h_new),
// p=pm25[:,tnext] written into A cols 128/129 for the next hist step.
// ---------------------------------------------------------------------------
__global__ __launch_bounds__(256) void gru_mfma(
    float* __restrict__ h, unsigned short* __restrict__ A,
    const unsigned short* __restrict__ Wa, const float* __restrict__ barr,
    const float* __restrict__ fcw, const float* __restrict__ fcb,
    const float* __restrict__ pm25, int hist_next, int tnext)
{
    const int tid = threadIdx.x;
    const int w = tid >> 6, lane = tid & 63, q = lane >> 4, lq = lane & 15;
    const long rowbase = (long)blockIdx.x * 64;
    const int koff = q * 8;

    f32x4 acc[4][4][2];   // [gate][rowtile][colgroup]
    #pragma unroll
    for (int g = 0; g < 4; ++g)
        #pragma unroll
        for (int rt = 0; rt < 4; ++rt)
            #pragma unroll
            for (int cg = 0; cg < 2; ++cg)
                #pragma unroll
                for (int e = 0; e < 4; ++e) acc[g][rt][cg][e] = 0.f;

    #pragma unroll
    for (int kc = 0; kc < 5; ++kc) {
        bf16x8 af[4];
        #pragma unroll
        for (int rt = 0; rt < 4; ++rt)
            af[rt] = *(const bf16x8*)(A + (rowbase + rt * 16 + lq) * KA + kc * 32 + koff);
        bf16x8 bfr[4][2];
        #pragma unroll
        for (int g = 0; g < 4; ++g)
            #pragma unroll
            for (int cg = 0; cg < 2; ++cg)
                bfr[g][cg] = *(const bf16x8*)(Wa + (long)(g * 128 + w * 32 + cg * 16 + lq) * KA + kc * 32 + koff);
        #pragma unroll
        for (int g = 0; g < 4; ++g)
            #pragma unroll
            for (int rt = 0; rt < 4; ++rt)
                #pragma unroll
                for (int cg = 0; cg < 2; ++cg)
                    acc[g][rt][cg] = __builtin_amdgcn_mfma_f32_16x16x32_bf16(
                        af[rt], bfr[g][cg], acc[g][rt][cg], 0, 0, 0);
    }

    // all A-reads (h cols) must complete before epilogue overwrites A h cols
    __syncthreads();

    float bias[4][2], fcwv[2];
    #pragma unroll
    for (int g = 0; g < 4; ++g)
        #pragma unroll
        for (int cg = 0; cg < 2; ++cg)
            bias[g][cg] = barr[g * 128 + w * 32 + cg * 16 + lq];
    fcwv[0] = fcw[w * 32 + lq];
    fcwv[1] = fcw[w * 32 + 16 + lq];

    float part[4][4];
    #pragma unroll
    for (int rt = 0; rt < 4; ++rt) {
        #pragma unroll
        for (int rg = 0; rg < 4; ++rg) {
            long row = rowbase + rt * 16 + q * 4 + rg;
            float psum = 0.f;
            #pragma unroll
            for (int cg = 0; cg < 2; ++cg) {
                int j = w * 32 + cg * 16 + lq;
                float rr = sigmoidf_(acc[0][rt][cg][rg] + bias[0][cg]);
                float zz = sigmoidf_(acc[1][rt][cg][rg] + bias[1][cg]);
                float nn2 = tanhf_(acc[3][rt][cg][rg] + bias[3][cg]
                                   + rr * (acc[2][rt][cg][rg] + bias[2][cg]));
                float hp = h[row * HH + j];
                float hn = (1.f - zz) * nn2 + zz * hp;
                h[row * HH + j] = hn;
                A[row * KA + j] = f2bf(hn);
                psum += fcwv[cg] * hn;
            }
            part[rt][rg] = psum;
        }
    }

    __shared__ float partS[4][64];
    if (hist_next) {
        #pragma unroll
        for (int rt = 0; rt < 4; ++rt)
            #pragma unroll
            for (int rg = 0; rg < 4; ++rg) {
                float v = part[rt][rg];
                v += __shfl_xor(v, 1);
                v += __shfl_xor(v, 2);
                v += __shfl_xor(v, 4);
                v += __shfl_xor(v, 8);
                if (lq == 0) partS[w][rt * 16 + q * 4 + rg] = v;
            }
    }
    __syncthreads();
    if (hist_next && tid < 64) {
        long row = rowbase + tid;
        int b = (int)(row / NN), n = (int)(row - (long)b * NN);
        float xn = partS[0][tid] + partS[1][tid] + partS[2][tid] + partS[3][tid] + fcb[0];
        A[row * KA + 128] = f2bf(xn);
        A[row * KA + 129] = f2bf(pm25[(long)b * (TH * NN) + (long)tnext * NN + n]);
    }
}

// ---------------------------------------------------------------------------
// Graph step: one block per batch. xn=fc(h) (+pred write), wind mask via
// packed P, transposed bitmask + ffs-walk ChebConv, writes x2 as bf16 into A.
// ---------------------------------------------------------------------------
__global__ __launch_bounds__(256) void graph_step(
    const float* __restrict__ h,
    const float* __restrict__ feature_t,   // feature + (TH+t)*NN*FF
    const float2* __restrict__ P,
    const float* __restrict__ fcw, const float* __restrict__ fcb,
    const float* __restrict__ w0, const float* __restrict__ w1,
    const float* __restrict__ cb,
    unsigned short* __restrict__ A,
    float* __restrict__ pred, int t)
{
    const int b = blockIdx.x;
    const int tid = threadIdx.x;

    __shared__ float fs[NN * FF];
    __shared__ float xs[NN * 9];
    __shared__ float dinv_s[NN];
    __shared__ float hz_s[NN];
    __shared__ unsigned long long maskT[NN][3];   // bits over source node i

    for (int i = tid; i < NN * 3; i += 256)
        ((unsigned long long*)maskT)[i] = 0ull;
    const float* fbase = feature_t + (long)b * (48 * NN * FF);
    for (int i = tid; i < NN * FF; i += 256) fs[i] = fbase[i];

    float xnv = 0.f;
    if (tid < NN) {
        const float4* h4 = (const float4*)(h + ((long)b * NN + tid) * HH);
        const float4* f4 = (const float4*)fcw;
        float s = 0.f;
        #pragma unroll 8
        for (int k = 0; k < 32; ++k) {
            float4 a = h4[k], wv = f4[k];
            s += a.x * wv.x + a.y * wv.y + a.z * wv.z + a.w * wv.w;
        }
        xnv = s + fcb[0];
    }
    __syncthreads();   // fs + maskT zero ready

    if (tid < NN) {
        if (t > 0) pred[((long)b * TF + (t - 1)) * NN + tid] = xnv;
        xs[tid * 9 + 0] = xnv;
        #pragma unroll
        for (int c = 0; c < FF; ++c) xs[tid * 9 + 1 + c] = fs[tid * FF + c];

        // phase A: wind-gated edges from source i = tid
        int i = tid;
        float u = fs[i * FF + 0], v = fs[i * FF + 1];
        const float2* Pr = P + (long)i * NN;
        unsigned long long selfbit = 1ull << (i & 63);
        int iw = i >> 6;
        int deg = 0;
        for (int jj = 0; jj < NN; ++jj) {
            float2 p = Pr[jj];
            if (u * p.x + v * p.y >= 0.5f) {
                deg++;
                atomicOr(&maskT[jj][iw], selfbit);
            }
        }
        dinv_s[i] = (deg > 0) ? rsqrtf((float)deg) : 0.f;
        hz_s[i] = (deg > 0) ? 0.f : -1.f;
    }
    __syncthreads();

    // phase B: walk set bits of column j's source mask
    if (tid < NN) {
        int j = tid;
        float acc9[9];
        #pragma unroll
        for (int c = 0; c < 9; ++c) acc9[c] = 0.f;
        #pragma unroll
        for (int wd = 0; wd < 3; ++wd) {
            unsigned long long m = maskT[j][wd];
            while (m) {
                int bp = __ffsll(m) - 1;
                m &= (m - 1);
                int i = wd * 64 + bp;
                float d = dinv_s[i];
                #pragma unroll
                for (int c = 0; c < 9; ++c) acc9[c] += d * xs[i * 9 + c];
            }
        }
        float dj = dinv_s[j], hzj = hz_s[j];
        float gsum = cb[0];
        unsigned short* out = A + ((long)b * NN + j) * KA + 128;
        #pragma unroll
        for (int c = 0; c < 9; ++c) {
            float xv = xs[j * 9 + c];
            float y = -dj * acc9[c] + hzj * xv;
            gsum += xv * w0[c] + y * w1[c];
            out[c] = f2bf(xv);
        }
        out[9] = f2bf(sigmoidf_(gsum));
    }
}

// final prediction slot t=TF-1: pred[:,23,:] = fc_out(h)
__global__ void final_pred(const float* __restrict__ h,
                           const float* __restrict__ fcw,
                           const float* __restrict__ fcb,
                           float* __restrict__ pred) {
    long r = (long)blockIdx.x * 256 + threadIdx.x;
    if (r < BN) {
        int b = (int)(r / NN), n = (int)(r - (long)b * NN);
        const float4* h4 = (const float4*)(h + r * HH);
        const float4* f4 = (const float4*)fcw;
        float s = 0.f;
        #pragma unroll 8
        for (int k = 0; k < 32; ++k) {
            float4 a = h4[k], wv = f4[k];
            s += a.x * wv.x + a.y * wv.y + a.z * wv.z + a.w * wv.w;
        }
        pred[((long)b * TF + (TF - 1)) * NN + n] = s + fcb[0];
    }
}

extern "C" void kernel_launch(void* const* d_in, const int* in_sizes, int n_in,
                              void* d_out, int out_size, void* d_ws, size_t ws_size,
                              hipStream_t stream) {
    const float* feature = (const float*)d_in[0];
    const float* pm25    = (const float*)d_in[1];
    const float* adj     = (const float*)d_in[2];
    const float* angles  = (const float*)d_in[3];
    const float* W_ih_h  = (const float*)d_in[4];
    const float* W_hh_h  = (const float*)d_in[5];
    const float* b_ih_h  = (const float*)d_in[6];
    const float* b_hh_h  = (const float*)d_in[7];
    const float* fch_w   = (const float*)d_in[8];
    const float* fch_b   = (const float*)d_in[9];
    const float* cw0     = (const float*)d_in[10];
    const float* cw1     = (const float*)d_in[11];
    const float* cbb     = (const float*)d_in[12];
    const float* W_ih    = (const float*)d_in[13];
    const float* W_hh    = (const float*)d_in[14];
    const float* b_ih    = (const float*)d_in[15];
    const float* b_hh    = (const float*)d_in[16];
    const float* fco_w   = (const float*)d_in[17];
    const float* fco_b   = (const float*)d_in[18];
    float* pred = (float*)d_out;

    char* ws = (char*)d_ws;
    size_t off = 0;
    float*          h    = (float*)(ws + off);          off += (size_t)BN * HH * 4;        // 24,117,248
    unsigned short* A    = (unsigned short*)(ws + off); off += (size_t)BN * KA * 2;        // 15,073,280
    unsigned short* WaH  = (unsigned short*)(ws + off); off += (size_t)NG * KA * 2;        //    163,840
    unsigned short* WaF  = (unsigned short*)(ws + off); off += (size_t)NG * KA * 2;
    float*          barrH= (float*)(ws + off);          off += (size_t)NG * 4;             //      2,048
    float*          barrF= (float*)(ws + off);          off += (size_t)NG * 4;
    float2*         P    = (float2*)(ws + off);         off += (size_t)NN * NN * 8;        //    270,848

    hipMemsetAsync(h, 0, (size_t)BN * HH * 4, stream);
    hipMemsetAsync(A, 0, (size_t)BN * KA * 2, stream);
    prep_weights<<<(NG * KA + 255) / 256, 256, 0, stream>>>(
        W_hh_h, W_ih_h, W_hh, W_ih, b_ih_h, b_hh_h, b_ih, b_hh,
        WaH, WaF, barrH, barrF);
    prep_P<<<(NN * NN + 255) / 256, 256, 0, stream>>>(angles, adj, P);
    init_hist_x<<<(BN + 255) / 256, 256, 0, stream>>>(pm25, A);

    for (int t = 0; t < TH; ++t) {
        gru_mfma<<<BN / 64, 256, 0, stream>>>(
            h, A, WaH, barrH, fch_w, fch_b, pm25,
            (t < TH - 1) ? 1 : 0, t + 1);
    }

    for (int t = 0; t < TF; ++t) {
        graph_step<<<BB, 256, 0, stream>>>(
            h, feature + (long)(TH + t) * NN * FF, P,
            (t == 0) ? fch_w : fco_w, (t == 0) ? fch_b : fco_b,
            cw0, cw1, cbb, A, pred, t);
        gru_mfma<<<BN / 64, 256, 0, stream>>>(
            h, A, WaF, barrF, fco_w, fco_b, pm25, 0, 0);
    }

    final_pred<<<(BN + 255) / 256, 256, 0, stream>>>(h, fco_w, fco_b, pred);
}

// Round 4
// 1165.030 us; speedup vs baseline: 33.8770x; 2.3263x over previous
//
#include <hip/hip_runtime.h>
#include <math.h>

#define BB 256
#define NN 184
#define HH 128
#define FF 8
#define TH 24
#define TF 24
#define BN (BB*NN)   // 47104
#define KA 160       // augmented K (128 h + up to 10 x + pad)
#define NG 512       // 4 gate-parts x 128
#define RPAD 192     // padded row count (12 tiles of 16)
#define STRH 136     // Ah row stride (elems): 272B, 16B-aligned, 2-way-bank (free)
#define STRX 40      // Ax row stride (elems): 80B, 16B-aligned, 2-way-bank (free)

typedef __attribute__((ext_vector_type(8))) short bf16x8;
typedef __attribute__((ext_vector_type(4))) float f32x4;

__device__ __forceinline__ float sigmoidf_(float x) {
    return 1.0f / (1.0f + __expf(-x));
}
__device__ __forceinline__ float tanhf_(float x) {
    float s = (x >= 0.f) ? 1.f : -1.f;
    float e = __expf(-2.0f * fabsf(x));
    return s * (1.0f - e) / (1.0f + e);
}
__device__ __forceinline__ unsigned short f2bf(float f) {
    unsigned u = __float_as_uint(f);
    u += 0x7fffu + ((u >> 16) & 1u);
    return (unsigned short)(u >> 16);
}

// ---------------------------------------------------------------------------
// Build augmented bf16 weights Wa[512][160] for hist & fore, and bias arrays
// barr[4][128]: R:bih+bhh, Z:bih+bhh, NH:bhh, NX:bih. (unchanged from r3)
// ---------------------------------------------------------------------------
__global__ void prep_weights(const float* __restrict__ WhhH, const float* __restrict__ WihH,
                             const float* __restrict__ WhhF, const float* __restrict__ WihF,
                             const float* __restrict__ bihH, const float* __restrict__ bhhH,
                             const float* __restrict__ bihF, const float* __restrict__ bhhF,
                             unsigned short* __restrict__ WaH, unsigned short* __restrict__ WaF,
                             float* __restrict__ barrH, float* __restrict__ barrF) {
    int idx = blockIdx.x * 256 + threadIdx.x;
    if (idx < NG * KA) {
        int jp = idx / KA, k = idx % KA;
        int j = jp & 127, part = jp >> 7;
        float vh = 0.f, vf = 0.f;
        if (part <= 1) {              // R, Z: combined Whh | Wih
            int row = part * 128 + j;
            if (k < 128) { vh = WhhH[row * 128 + k]; vf = WhhF[row * 128 + k]; }
            else {
                if (k < 130) vh = WihH[row * 2 + (k - 128)];
                if (k < 138) vf = WihF[row * 10 + (k - 128)];
            }
        } else if (part == 2) {       // NH: h part of n-gate
            if (k < 128) { vh = WhhH[(256 + j) * 128 + k]; vf = WhhF[(256 + j) * 128 + k]; }
        } else {                      // NX: x part of n-gate
            if (k >= 128) {
                if (k < 130) vh = WihH[(256 + j) * 2 + (k - 128)];
                if (k < 138) vf = WihF[(256 + j) * 10 + (k - 128)];
            }
        }
        WaH[idx] = f2bf(vh); WaF[idx] = f2bf(vf);
    }
    if (idx < NG) {
        int j = idx & 127, part = idx >> 7;
        float bh, bf2;
        if (part == 0)      { bh = bihH[j] + bhhH[j];             bf2 = bihF[j] + bhhF[j]; }
        else if (part == 1) { bh = bihH[128 + j] + bhhH[128 + j]; bf2 = bihF[128 + j] + bhhF[128 + j]; }
        else if (part == 2) { bh = bhhH[256 + j];                 bf2 = bhhF[256 + j]; }
        else                { bh = bihH[256 + j];                 bf2 = bihF[256 + j]; }
        barrH[idx] = bh; barrF[idx] = bf2;
    }
}

// ---------------------------------------------------------------------------
// Sparse edge list over adj: rec = (c1, c2, i, j) as float4. Order is
// nondeterministic (atomic append) but consumers are order-invariant.
// ---------------------------------------------------------------------------
__global__ void prep_edges(const float* __restrict__ angles, const float* __restrict__ adj,
                           float4* __restrict__ edges, int* __restrict__ cnt) {
    int idx = blockIdx.x * 256 + threadIdx.x;
    if (idx < NN * NN && adj[idx] > 0.f) {
        float a = angles[idx];
        int pos = atomicAdd(cnt, 1);
        float4 r;
        r.x = cosf(a);
        r.y = cosf(a - 1.57079632679489662f);
        r.z = __int_as_float(idx / NN);   // i (source)
        r.w = __int_as_float(idx % NN);   // j (dest)
        edges[pos] = r;
    }
}

// ---------------------------------------------------------------------------
// Persistent fused kernel: one block per batch, 512 threads (8 waves).
// Wave w owns h-cols [16w,16w+16) for all 4 gate parts; weights live in
// VGPRs for the whole phase. h bf16 double-buffered in LDS; h fp32 in
// global (L2-resident per CU). 24 hist + 24 (graph+GRU) fore steps inline.
// ---------------------------------------------------------------------------
__global__ __launch_bounds__(512) void fused_dgc(
    const float* __restrict__ feature,
    const float* __restrict__ pm25,
    float* __restrict__ h,                 // [BN][128] fp32 state
    const unsigned short* __restrict__ WaH, const float* __restrict__ barrH,
    const unsigned short* __restrict__ WaF, const float* __restrict__ barrF,
    const float* __restrict__ fchw, const float* __restrict__ fchb,
    const float* __restrict__ fcow, const float* __restrict__ fcob,
    const float* __restrict__ cw0, const float* __restrict__ cw1,
    const float* __restrict__ cbb,
    const float4* __restrict__ edges, const int* __restrict__ ecnt,
    float* __restrict__ pred)
{
    __shared__ unsigned short Ah[2][RPAD * STRH];   // 104,448 B
    __shared__ unsigned short Ax[RPAD * STRX];      //  15,360 B
    __shared__ float xn_s[RPAD];
    __shared__ float partS[8][RPAD];                //   6,144 B
    __shared__ float fs[NN * FF];                   //   5,888 B
    __shared__ unsigned long long maskT[NN][3];     //   4,416 B
    __shared__ int deg_s[NN];
    __shared__ float dinv_s[NN];
    __shared__ float hz_s[NN];

    const int tid = threadIdx.x;
    const int bb = blockIdx.x;
    const int w = tid >> 6, lane = tid & 63, q = lane >> 4, lq = lane & 15;
    const int jcol = w * 16 + lq;          // owned h-column, 0..127
    const long rowbase = (long)bb * NN;

    // ---- init LDS state ----
    for (int i = tid; i < RPAD * STRH; i += 512) Ah[0][i] = 0;
    for (int i = tid; i < RPAD * STRX; i += 512) Ax[i] = 0;
    __syncthreads();
    if (tid < NN)
        Ax[tid * STRX + 1] = f2bf(pm25[(long)bb * TH * NN + tid]);   // p at t=0

    // ---- phase weights in registers ----
    bf16x8 wreg[4][5];
    float bias[4], fcwv, fcb0;
    #pragma unroll
    for (int g = 0; g < 4; ++g) {
        bias[g] = barrH[g * 128 + jcol];
        #pragma unroll
        for (int kc = 0; kc < 5; ++kc)
            wreg[g][kc] = *(const bf16x8*)(WaH + (long)(g * 128 + jcol) * KA + kc * 32 + q * 8);
    }
    fcwv = fchw[jcol]; fcb0 = fchb[0];
    __syncthreads();

    int p = 0;   // Ah read-buffer parity

    // GEMM + gate epilogue over 12 row-tiles; reads Ah[p]/Ax, writes Ah[p^1],
    // h fp32, and per-wave fc partials into partS.
    auto gemm_epi = [&]() {
        for (int rt = 0; rt < 12; ++rt) {
            float hp4[4];
            #pragma unroll
            for (int rg = 0; rg < 4; ++rg) {
                int r = rt * 16 + q * 4 + rg;
                hp4[rg] = (r < NN) ? h[(rowbase + r) * HH + jcol] : 0.f;
            }
            f32x4 acc0 = {0.f,0.f,0.f,0.f}, acc1 = {0.f,0.f,0.f,0.f};
            f32x4 acc2 = {0.f,0.f,0.f,0.f}, acc3 = {0.f,0.f,0.f,0.f};
            #pragma unroll
            for (int kc = 0; kc < 4; ++kc) {
                bf16x8 af = *(const bf16x8*)(&Ah[p][(rt * 16 + lq) * STRH + kc * 32 + q * 8]);
                acc0 = __builtin_amdgcn_mfma_f32_16x16x32_bf16(af, wreg[0][kc], acc0, 0, 0, 0);
                acc1 = __builtin_amdgcn_mfma_f32_16x16x32_bf16(af, wreg[1][kc], acc1, 0, 0, 0);
                acc2 = __builtin_amdgcn_mfma_f32_16x16x32_bf16(af, wreg[2][kc], acc2, 0, 0, 0);
                acc3 = __builtin_amdgcn_mfma_f32_16x16x32_bf16(af, wreg[3][kc], acc3, 0, 0, 0);
            }
            {
                bf16x8 ax = *(const bf16x8*)(&Ax[(rt * 16 + lq) * STRX + q * 8]);
                acc0 = __builtin_amdgcn_mfma_f32_16x16x32_bf16(ax, wreg[0][4], acc0, 0, 0, 0);
                acc1 = __builtin_amdgcn_mfma_f32_16x16x32_bf16(ax, wreg[1][4], acc1, 0, 0, 0);
                acc2 = __builtin_amdgcn_mfma_f32_16x16x32_bf16(ax, wreg[2][4], acc2, 0, 0, 0);
                acc3 = __builtin_amdgcn_mfma_f32_16x16x32_bf16(ax, wreg[3][4], acc3, 0, 0, 0);
            }
            #pragma unroll
            for (int rg = 0; rg < 4; ++rg) {
                int r = rt * 16 + q * 4 + rg;
                float rr  = sigmoidf_(acc0[rg] + bias[0]);
                float zz  = sigmoidf_(acc1[rg] + bias[1]);
                float nn2 = tanhf_(acc3[rg] + bias[3] + rr * (acc2[rg] + bias[2]));
                float hn = (1.f - zz) * nn2 + zz * hp4[rg];
                if (r < NN) h[(rowbase + r) * HH + jcol] = hn;
                Ah[p ^ 1][r * STRH + jcol] = f2bf(hn);
                float v = fcwv * hn;
                v += __shfl_xor(v, 1); v += __shfl_xor(v, 2);
                v += __shfl_xor(v, 4); v += __shfl_xor(v, 8);
                if (lq == 0) partS[w][r] = v;
            }
        }
    };

    // ================= HIST: 24 steps =================
    for (int t = 0; t < TH; ++t) {
        gemm_epi();
        __syncthreads();
        if (tid < NN) {
            float xn = fcb0;
            #pragma unroll
            for (int ww = 0; ww < 8; ++ww) xn += partS[ww][tid];
            xn_s[tid] = xn;
            if (t < TH - 1) {
                Ax[tid * STRX + 0] = f2bf(xn);
                Ax[tid * STRX + 1] = f2bf(pm25[((long)bb * TH + t + 1) * NN + tid]);
            }
        }
        __syncthreads();
        p ^= 1;
    }

    // ---- switch to fore weights ----
    #pragma unroll
    for (int g = 0; g < 4; ++g) {
        bias[g] = barrF[g * 128 + jcol];
        #pragma unroll
        for (int kc = 0; kc < 5; ++kc)
            wreg[g][kc] = *(const bf16x8*)(WaF + (long)(g * 128 + jcol) * KA + kc * 32 + q * 8);
    }
    fcwv = fcow[jcol]; fcb0 = fcob[0];
    float w0r[9], w1r[9];
    #pragma unroll
    for (int c = 0; c < 9; ++c) { w0r[c] = cw0[c]; w1r[c] = cw1[c]; }
    const float cb0 = cbb[0];
    const int nE = *ecnt;

    // ================= FORE: 24 steps =================
    for (int t = 0; t < TF; ++t) {
        // ---- graph: features + wind mask + ChebConv gate ----
        const float4* fb4 = (const float4*)(feature + ((long)bb * 48 + TH + t) * NN * FF);
        for (int i = tid; i < NN * FF / 4; i += 512) ((float4*)fs)[i] = fb4[i];
        for (int i = tid; i < NN * 3; i += 512) ((unsigned long long*)maskT)[i] = 0ull;
        for (int i = tid; i < NN; i += 512) deg_s[i] = 0;
        __syncthreads();
        for (int e = tid; e < nE; e += 512) {
            float4 rec = edges[e];
            int ii = __float_as_int(rec.z), jj = __float_as_int(rec.w);
            if (fs[ii * FF] * rec.x + fs[ii * FF + 1] * rec.y >= 0.5f) {
                atomicAdd(&deg_s[ii], 1);
                atomicOr(&maskT[jj][ii >> 6], 1ull << (ii & 63));
            }
        }
        __syncthreads();
        if (tid < NN) {
            int d = deg_s[tid];
            dinv_s[tid] = (d > 0) ? rsqrtf((float)d) : 0.f;
            hz_s[tid] = (d > 0) ? 0.f : -1.f;
            Ax[tid * STRX + 0] = f2bf(xn_s[tid]);
            #pragma unroll
            for (int c = 0; c < FF; ++c)
                Ax[tid * STRX + 1 + c] = f2bf(fs[tid * FF + c]);
        }
        __syncthreads();
        if (tid < NN) {
            int j = tid;
            float acc9[9];
            #pragma unroll
            for (int c = 0; c < 9; ++c) acc9[c] = 0.f;
            #pragma unroll
            for (int wd = 0; wd < 3; ++wd) {
                unsigned long long m = maskT[j][wd];
                while (m) {
                    int bp = __ffsll((unsigned long long)m) - 1;
                    m &= m - 1;
                    int i = wd * 64 + bp;
                    float d = dinv_s[i];
                    acc9[0] += d * xn_s[i];
                    #pragma unroll
                    for (int c = 1; c < 9; ++c) acc9[c] += d * fs[i * FF + c - 1];
                }
            }
            float dj = dinv_s[j], hzj = hz_s[j];
            float gsum = cb0;
            #pragma unroll
            for (int c = 0; c < 9; ++c) {
                float xv = (c == 0) ? xn_s[j] : fs[j * FF + c - 1];
                float y = -dj * acc9[c] + hzj * xv;
                gsum += xv * w0r[c] + y * w1r[c];
            }
            Ax[j * STRX + 9] = f2bf(sigmoidf_(gsum));
        }
        __syncthreads();
        // ---- GRU ----
        gemm_epi();
        __syncthreads();
        if (tid < NN) {
            float xn = fcb0;
            #pragma unroll
            for (int ww = 0; ww < 8; ++ww) xn += partS[ww][tid];
            xn_s[tid] = xn;
            pred[((long)bb * TF + t) * NN + tid] = xn;
        }
        __syncthreads();
        p ^= 1;
    }
}

extern "C" void kernel_launch(void* const* d_in, const int* in_sizes, int n_in,
                              void* d_out, int out_size, void* d_ws, size_t ws_size,
                              hipStream_t stream) {
    const float* feature = (const float*)d_in[0];
    const float* pm25    = (const float*)d_in[1];
    const float* adj     = (const float*)d_in[2];
    const float* angles  = (const float*)d_in[3];
    const float* W_ih_h  = (const float*)d_in[4];
    const float* W_hh_h  = (const float*)d_in[5];
    const float* b_ih_h  = (const float*)d_in[6];
    const float* b_hh_h  = (const float*)d_in[7];
    const float* fch_w   = (const float*)d_in[8];
    const float* fch_b   = (const float*)d_in[9];
    const float* cw0     = (const float*)d_in[10];
    const float* cw1     = (const float*)d_in[11];
    const float* cbb     = (const float*)d_in[12];
    const float* W_ih    = (const float*)d_in[13];
    const float* W_hh    = (const float*)d_in[14];
    const float* b_ih    = (const float*)d_in[15];
    const float* b_hh    = (const float*)d_in[16];
    const float* fco_w   = (const float*)d_in[17];
    const float* fco_b   = (const float*)d_in[18];
    float* pred = (float*)d_out;

    char* ws = (char*)d_ws;
    size_t off = 0;
    float*          h     = (float*)(ws + off);          off += (size_t)BN * HH * 4;     // 24,117,248
    unsigned short* WaH   = (unsigned short*)(ws + off); off += (size_t)NG * KA * 2;     //    163,840
    unsigned short* WaF   = (unsigned short*)(ws + off); off += (size_t)NG * KA * 2;
    float*          barrH = (float*)(ws + off);          off += (size_t)NG * 4;
    float*          barrF = (float*)(ws + off);          off += (size_t)NG * 4;
    float4*         edges = (float4*)(ws + off);         off += (size_t)NN * NN * 16;    //    541,696
    int*            cnt   = (int*)(ws + off);            off += 16;

    hipMemsetAsync(h, 0, (size_t)BN * HH * 4, stream);
    hipMemsetAsync(cnt, 0, 16, stream);
    prep_weights<<<(NG * KA + 255) / 256, 256, 0, stream>>>(
        W_hh_h, W_ih_h, W_hh, W_ih, b_ih_h, b_hh_h, b_ih, b_hh,
        WaH, WaF, barrH, barrF);
    prep_edges<<<(NN * NN + 255) / 256, 256, 0, stream>>>(angles, adj, edges, cnt);

    fused_dgc<<<BB, 512, 0, stream>>>(
        feature, pm25, h, WaH, barrH, WaF, barrF,
        fch_w, fch_b, fco_w, fco_b, cw0, cw1, cbb,
        edges, cnt, pred);
}

// Round 5
// 910.981 us; speedup vs baseline: 43.3244x; 1.2789x over previous
//
#include <hip/hip_runtime.h>
#include <math.h>

#define BB 256
#define NN 184
#define HH 128
#define FF 8
#define TH 24
#define TF 24
#define KA 160       // augmented K (128 h + up to 10 x + pad)
#define NG 512       // 4 gate-parts x 128
#define RPAD 192     // padded row count (12 tiles of 16)
#define STRH 136     // Ah row stride (elems): 272B; b128 reads land 2-way (free)
#define STRX 40      // Ax row stride (elems): 80B

typedef __attribute__((ext_vector_type(8))) short bf16x8;
typedef __attribute__((ext_vector_type(4))) float f32x4;

__device__ __forceinline__ float sigmoidf_(float x) {
    return 1.0f / (1.0f + __expf(-x));
}
__device__ __forceinline__ float tanhf_(float x) {
    float s = (x >= 0.f) ? 1.f : -1.f;
    float e = __expf(-2.0f * fabsf(x));
    return s * (1.0f - e) / (1.0f + e);
}
__device__ __forceinline__ unsigned short f2bf(float f) {
    unsigned u = __float_as_uint(f);
    u += 0x7fffu + ((u >> 16) & 1u);
    return (unsigned short)(u >> 16);
}

// ---------------------------------------------------------------------------
// Build augmented bf16 weights Wa[512][160] (R, Z, NH, NX gate parts) and
// bias arrays barr[4][128]: R:bih+bhh, Z:bih+bhh, NH:bhh, NX:bih.
// ---------------------------------------------------------------------------
__global__ void prep_weights(const float* __restrict__ WhhH, const float* __restrict__ WihH,
                             const float* __restrict__ WhhF, const float* __restrict__ WihF,
                             const float* __restrict__ bihH, const float* __restrict__ bhhH,
                             const float* __restrict__ bihF, const float* __restrict__ bhhF,
                             unsigned short* __restrict__ WaH, unsigned short* __restrict__ WaF,
                             float* __restrict__ barrH, float* __restrict__ barrF) {
    int idx = blockIdx.x * 256 + threadIdx.x;
    if (idx < NG * KA) {
        int jp = idx / KA, k = idx % KA;
        int j = jp & 127, part = jp >> 7;
        float vh = 0.f, vf = 0.f;
        if (part <= 1) {              // R, Z: combined Whh | Wih
            int row = part * 128 + j;
            if (k < 128) { vh = WhhH[row * 128 + k]; vf = WhhF[row * 128 + k]; }
            else {
                if (k < 130) vh = WihH[row * 2 + (k - 128)];
                if (k < 138) vf = WihF[row * 10 + (k - 128)];
            }
        } else if (part == 2) {       // NH: h part of n-gate
            if (k < 128) { vh = WhhH[(256 + j) * 128 + k]; vf = WhhF[(256 + j) * 128 + k]; }
        } else {                      // NX: x part of n-gate
            if (k >= 128) {
                if (k < 130) vh = WihH[(256 + j) * 2 + (k - 128)];
                if (k < 138) vf = WihF[(256 + j) * 10 + (k - 128)];
            }
        }
        WaH[idx] = f2bf(vh); WaF[idx] = f2bf(vf);
    }
    if (idx < NG) {
        int j = idx & 127, part = idx >> 7;
        float bh, bf2;
        if (part == 0)      { bh = bihH[j] + bhhH[j];             bf2 = bihF[j] + bhhF[j]; }
        else if (part == 1) { bh = bihH[128 + j] + bhhH[128 + j]; bf2 = bihF[128 + j] + bhhF[128 + j]; }
        else if (part == 2) { bh = bhhH[256 + j];                 bf2 = bhhF[256 + j]; }
        else                { bh = bihH[256 + j];                 bf2 = bihF[256 + j]; }
        barrH[idx] = bh; barrF[idx] = bf2;
    }
}

// ---------------------------------------------------------------------------
// Sparse edge list over adj: rec = (c1, c2, i, j) as float4 (order-invariant
// consumers, atomic append).
// ---------------------------------------------------------------------------
__global__ void prep_edges(const float* __restrict__ angles, const float* __restrict__ adj,
                           float4* __restrict__ edges, int* __restrict__ cnt) {
    int idx = blockIdx.x * 256 + threadIdx.x;
    if (idx < NN * NN && adj[idx] > 0.f) {
        float a = angles[idx];
        int pos = atomicAdd(cnt, 1);
        float4 r;
        r.x = cosf(a);
        r.y = cosf(a - 1.57079632679489662f);
        r.z = __int_as_float(idx / NN);   // i (source)
        r.w = __int_as_float(idx % NN);   // j (dest)
        edges[pos] = r;
    }
}

// ---------------------------------------------------------------------------
// Persistent fused kernel: one block per batch, 512 threads (8 waves).
// h fp32 lives ENTIRELY in registers (hreg[48]/thread); h bf16 double-
// buffered in LDS for MFMA A-operands. Weights (15 nonzero gate-chunks)
// in VGPRs per phase. fc(h) computed by a one-column-B MFMA pass.
// ---------------------------------------------------------------------------
__global__ __launch_bounds__(512, 2) void fused_dgc(
    const float* __restrict__ feature,
    const float* __restrict__ pm25,
    const unsigned short* __restrict__ WaH, const float* __restrict__ barrH,
    const unsigned short* __restrict__ WaF, const float* __restrict__ barrF,
    const float* __restrict__ fchw, const float* __restrict__ fchb,
    const float* __restrict__ fcow, const float* __restrict__ fcob,
    const float* __restrict__ cw0, const float* __restrict__ cw1,
    const float* __restrict__ cbb,
    const float4* __restrict__ edges, const int* __restrict__ ecnt,
    float* __restrict__ pred)
{
    __shared__ unsigned short Ah[2][RPAD * STRH];   // 104,448 B
    __shared__ unsigned short Ax[RPAD * STRX];      //  15,360 B
    __shared__ float xn_s[RPAD];
    __shared__ float fs[NN * FF];                   //   5,888 B
    __shared__ unsigned long long maskT[NN][3];     //   4,416 B
    __shared__ int deg_s[NN];
    __shared__ float dinv_s[NN];
    __shared__ float hz_s[NN];

    const int tid = threadIdx.x;
    const int bb = blockIdx.x;
    const int w = tid >> 6, lane = tid & 63, q = lane >> 4, lq = lane & 15;
    const int jcol = w * 16 + lq;          // owned h-column, 0..127

    for (int i = tid; i < RPAD * STRH; i += 512) Ah[0][i] = 0;
    for (int i = tid; i < RPAD * STRX; i += 512) Ax[i] = 0;
    __syncthreads();
    if (tid < NN)
        Ax[tid * STRX + 1] = f2bf(pm25[(long)bb * TH * NN + tid]);   // p at t=0

    // ---- phase weights in registers (only nonzero chunks) ----
    bf16x8 wregH[3][4];   // g = R,Z,NH  : kc 0..3 (h part)
    bf16x8 wregX[3];      // g = R,Z,NX  : kc 4    (x part)
    bf16x8 fcfrag[4];     // fc weights as one-column B fragments
    float bias[4], fcb0;

    auto load_phase = [&](const unsigned short* Wa, const float* barr,
                          const float* fcw, const float* fcb) {
        #pragma unroll
        for (int g = 0; g < 3; ++g)
            #pragma unroll
            for (int kc = 0; kc < 4; ++kc)
                wregH[g][kc] = *(const bf16x8*)(Wa + (long)(g * 128 + jcol) * KA + kc * 32 + q * 8);
        wregX[0] = *(const bf16x8*)(Wa + (long)(0 * 128 + jcol) * KA + 128 + q * 8);
        wregX[1] = *(const bf16x8*)(Wa + (long)(1 * 128 + jcol) * KA + 128 + q * 8);
        wregX[2] = *(const bf16x8*)(Wa + (long)(3 * 128 + jcol) * KA + 128 + q * 8);
        #pragma unroll
        for (int g = 0; g < 4; ++g) bias[g] = barr[g * 128 + jcol];
        #pragma unroll
        for (int kc = 0; kc < 4; ++kc) {
            bf16x8 v;
            #pragma unroll
            for (int jj = 0; jj < 8; ++jj)
                v[jj] = (lq == 0) ? (short)f2bf(fcw[kc * 32 + q * 8 + jj]) : (short)0;
            fcfrag[kc] = v;
        }
        fcb0 = fcb[0];
    };
    load_phase(WaH, barrH, fchw, fchb);

    float w0r[9], w1r[9];
    #pragma unroll
    for (int c = 0; c < 9; ++c) { w0r[c] = cw0[c]; w1r[c] = cw1[c]; }
    const float cb0 = cbb[0];
    const int nE = *ecnt;

    float hreg[48];                        // fp32 h state: rows rt*4.. , col jcol
    #pragma unroll
    for (int i = 0; i < 48; ++i) hreg[i] = 0.f;

    int p = 0;

    for (int t = 0; t < TH + TF; ++t) {
        // ================= graph phase (fore steps only) =================
        if (t >= TH) {
            const float4* fb4 = (const float4*)(feature + ((long)bb * 48 + t) * (NN * FF));
            for (int i = tid; i < (NN * FF) / 4; i += 512) ((float4*)fs)[i] = fb4[i];
            for (int i = tid; i < NN * 3; i += 512) ((unsigned long long*)maskT)[i] = 0ull;
            for (int i = tid; i < NN; i += 512) deg_s[i] = 0;
            __syncthreads();
            for (int e = tid; e < nE; e += 512) {
                float4 rec = edges[e];
                int ii = __float_as_int(rec.z), jj = __float_as_int(rec.w);
                if (fs[ii * FF] * rec.x + fs[ii * FF + 1] * rec.y >= 0.5f) {
                    atomicAdd(&deg_s[ii], 1);
                    atomicOr(&maskT[jj][ii >> 6], 1ull << (ii & 63));
                }
            }
            __syncthreads();
            if (tid < NN) {
                int d = deg_s[tid];
                dinv_s[tid] = (d > 0) ? rsqrtf((float)d) : 0.f;
                hz_s[tid] = (d > 0) ? 0.f : -1.f;
                Ax[tid * STRX + 0] = f2bf(xn_s[tid]);
                #pragma unroll
                for (int c = 0; c < FF; ++c)
                    Ax[tid * STRX + 1 + c] = f2bf(fs[tid * FF + c]);
            }
            __syncthreads();
            if (tid < NN) {
                int j = tid;
                float acc9[9];
                #pragma unroll
                for (int c = 0; c < 9; ++c) acc9[c] = 0.f;
                #pragma unroll
                for (int wd = 0; wd < 3; ++wd) {
                    unsigned long long m = maskT[j][wd];
                    while (m) {
                        int bp = __ffsll((unsigned long long)m) - 1;
                        m &= m - 1;
                        int i = wd * 64 + bp;
                        float d = dinv_s[i];
                        acc9[0] += d * xn_s[i];
                        #pragma unroll
                        for (int c = 1; c < 9; ++c) acc9[c] += d * fs[i * FF + c - 1];
                    }
                }
                float dj = dinv_s[j], hzj = hz_s[j];
                float gsum = cb0;
                #pragma unroll
                for (int c = 0; c < 9; ++c) {
                    float xv = (c == 0) ? xn_s[j] : fs[j * FF + c - 1];
                    float y = -dj * acc9[c] + hzj * xv;
                    gsum += xv * w0r[c] + y * w1r[c];
                }
                Ax[j * STRX + 9] = f2bf(sigmoidf_(gsum));
            }
            __syncthreads();
        }

        // ================= GRU GEMM + gate epilogue =================
        #pragma unroll
        for (int rt = 0; rt < 12; ++rt) {
            f32x4 a0 = {0.f,0.f,0.f,0.f}, a1 = {0.f,0.f,0.f,0.f}, a2 = {0.f,0.f,0.f,0.f};
            #pragma unroll
            for (int kc = 0; kc < 4; ++kc) {
                bf16x8 af = *(const bf16x8*)(&Ah[p][(rt * 16 + lq) * STRH + kc * 32 + q * 8]);
                a0 = __builtin_amdgcn_mfma_f32_16x16x32_bf16(af, wregH[0][kc], a0, 0, 0, 0);
                a1 = __builtin_amdgcn_mfma_f32_16x16x32_bf16(af, wregH[1][kc], a1, 0, 0, 0);
                a2 = __builtin_amdgcn_mfma_f32_16x16x32_bf16(af, wregH[2][kc], a2, 0, 0, 0);
            }
            bf16x8 ax = *(const bf16x8*)(&Ax[(rt * 16 + lq) * STRX + q * 8]);
            a0 = __builtin_amdgcn_mfma_f32_16x16x32_bf16(ax, wregX[0], a0, 0, 0, 0);
            a1 = __builtin_amdgcn_mfma_f32_16x16x32_bf16(ax, wregX[1], a1, 0, 0, 0);
            f32x4 a3 = {0.f,0.f,0.f,0.f};
            a3 = __builtin_amdgcn_mfma_f32_16x16x32_bf16(ax, wregX[2], a3, 0, 0, 0);
            #pragma unroll
            for (int rg = 0; rg < 4; ++rg) {
                int r = rt * 16 + q * 4 + rg;
                float rr  = sigmoidf_(a0[rg] + bias[0]);
                float zz  = sigmoidf_(a1[rg] + bias[1]);
                float nn2 = tanhf_(a3[rg] + bias[3] + rr * (a2[rg] + bias[2]));
                float hn = (1.f - zz) * nn2 + zz * hreg[rt * 4 + rg];
                hreg[rt * 4 + rg] = hn;
                Ah[p ^ 1][r * STRH + jcol] = f2bf(hn);
            }
        }
        __syncthreads();

        // ================= fc pass: xn = fcw . h_new via one-col MFMA =====
        #pragma unroll
        for (int rr2 = 0; rr2 < 2; ++rr2) {
            int rt = w + rr2 * 8;
            if (rt < 12) {
                f32x4 fa = {0.f,0.f,0.f,0.f};
                #pragma unroll
                for (int kc = 0; kc < 4; ++kc) {
                    bf16x8 af = *(const bf16x8*)(&Ah[p ^ 1][(rt * 16 + lq) * STRH + kc * 32 + q * 8]);
                    fa = __builtin_amdgcn_mfma_f32_16x16x32_bf16(af, fcfrag[kc], fa, 0, 0, 0);
                }
                int rbase = rt * 16 + q * 4;
                if (lq == 0 && rbase < NN) {   // rbase%4==0; rbase<184 => rbase+4<=184
                    float4 xn4;
                    xn4.x = fa[0] + fcb0; xn4.y = fa[1] + fcb0;
                    xn4.z = fa[2] + fcb0; xn4.w = fa[3] + fcb0;
                    *(float4*)&xn_s[rbase] = xn4;
                    if (t >= TH) {
                        *(float4*)(pred + ((long)bb * TF + (t - TH)) * NN + rbase) = xn4;
                    } else if (t < TH - 1) {
                        float4 p4 = *(const float4*)(pm25 + ((long)bb * TH + t + 1) * NN + rbase);
                        Ax[(rbase + 0) * STRX + 0] = f2bf(xn4.x);
                        Ax[(rbase + 1) * STRX + 0] = f2bf(xn4.y);
                        Ax[(rbase + 2) * STRX + 0] = f2bf(xn4.z);
                        Ax[(rbase + 3) * STRX + 0] = f2bf(xn4.w);
                        Ax[(rbase + 0) * STRX + 1] = f2bf(p4.x);
                        Ax[(rbase + 1) * STRX + 1] = f2bf(p4.y);
                        Ax[(rbase + 2) * STRX + 1] = f2bf(p4.z);
                        Ax[(rbase + 3) * STRX + 1] = f2bf(p4.w);
                    }
                }
            }
        }
        __syncthreads();

        if (t == TH - 1)
            load_phase(WaF, barrF, fcow, fcob);
        p ^= 1;
    }
}

extern "C" void kernel_launch(void* const* d_in, const int* in_sizes, int n_in,
                              void* d_out, int out_size, void* d_ws, size_t ws_size,
                              hipStream_t stream) {
    const float* feature = (const float*)d_in[0];
    const float* pm25    = (const float*)d_in[1];
    const float* adj     = (const float*)d_in[2];
    const float* angles  = (const float*)d_in[3];
    const float* W_ih_h  = (const float*)d_in[4];
    const float* W_hh_h  = (const float*)d_in[5];
    const float* b_ih_h  = (const float*)d_in[6];
    const float* b_hh_h  = (const float*)d_in[7];
    const float* fch_w   = (const float*)d_in[8];
    const float* fch_b   = (const float*)d_in[9];
    const float* cw0     = (const float*)d_in[10];
    const float* cw1     = (const float*)d_in[11];
    const float* cbb     = (const float*)d_in[12];
    const float* W_ih    = (const float*)d_in[13];
    const float* W_hh    = (const float*)d_in[14];
    const float* b_ih    = (const float*)d_in[15];
    const float* b_hh    = (const float*)d_in[16];
    const float* fco_w   = (const float*)d_in[17];
    const float* fco_b   = (const float*)d_in[18];
    float* pred = (float*)d_out;

    char* ws = (char*)d_ws;
    size_t off = 0;
    unsigned short* WaH   = (unsigned short*)(ws + off); off += (size_t)NG * KA * 2;   // 163,840
    unsigned short* WaF   = (unsigned short*)(ws + off); off += (size_t)NG * KA * 2;
    float*          barrH = (float*)(ws + off);          off += (size_t)NG * 4;
    float*          barrF = (float*)(ws + off);          off += (size_t)NG * 4;
    float4*         edges = (float4*)(ws + off);         off += (size_t)NN * NN * 16;  // 541,696
    int*            cnt   = (int*)(ws + off);            off += 16;

    hipMemsetAsync(cnt, 0, 16, stream);
    prep_weights<<<(NG * KA + 255) / 256, 256, 0, stream>>>(
        W_hh_h, W_ih_h, W_hh, W_ih, b_ih_h, b_hh_h, b_ih, b_hh,
        WaH, WaF, barrH, barrF);
    prep_edges<<<(NN * NN + 255) / 256, 256, 0, stream>>>(angles, adj, edges, cnt);

    fused_dgc<<<BB, 512, 0, stream>>>(
        feature, pm25, WaH, barrH, WaF, barrF,
        fch_w, fch_b, fco_w, fco_b, cw0, cw1, cbb,
        edges, cnt, pred);
}